// Round 3
// baseline (742.558 us; speedup 1.0000x reference)
//
#include <hip/hip_runtime.h>
#include <hip/hip_bf16.h>
#include <stdint.h>

#define LOG2E 1.4426950408889634f
#define LN2   0.6931471805599453f
#define NEG  -1e30f

static constexpr int B = 64, T = 2000, C = 512, L = 200;
static constexpr int CH = 10;          // DP steps per prefetch chunk
static constexpr int NC = T / CH;      // 200 chunks (exact)

// round-to-nearest-even f32 -> bf16 (works for any finite sign)
static __device__ __forceinline__ uint16_t f2bf(float f) {
    uint32_t u = __float_as_uint(f);
    uint32_t r = (u + 0x7FFFu + ((u >> 16) & 1u)) >> 16;
    return (uint16_t)r;
}

// exact log2-domain logaddexp: log2(2^x + 2^y)
static __device__ __forceinline__ float lae2(float x, float y) {
    float m = fmaxf(x, y);
    float e = exp2f(-fabsf(x - y));
    return m + log2f(1.0f + e);
}

// Kernel A: per (b,t) row compute log2-softmax at the 200 target ids.
// One wave per row, 4 waves per block. emit[b,t,l] = log2 p[tgt] (bf16)
__global__ __launch_bounds__(256) void emit_kernel(
    const float* __restrict__ x, const int* __restrict__ tgt,
    uint16_t* __restrict__ emit)
{
    const int wid  = threadIdx.x >> 6;
    const int lane = threadIdx.x & 63;
    const int row  = blockIdx.x * 4 + wid;      // in [0, B*T), grid exact
    const int b    = row / T;
    const float* xr = x + (size_t)row * C;

    __shared__ float lds[4][C];
    float* e = lds[wid];                         // wave-private: no barrier

    const float4 v0 = *(const float4*)(xr + lane * 4);
    const float4 v1 = *(const float4*)(xr + C / 2 + lane * 4);

    *(float4*)&e[lane * 4]         = v0;         // raw logits in LDS
    *(float4*)&e[C / 2 + lane * 4] = v1;

    float m = fmaxf(fmaxf(fmaxf(v0.x, v0.y), fmaxf(v0.z, v0.w)),
                    fmaxf(fmaxf(v1.x, v1.y), fmaxf(v1.z, v1.w)));
    #pragma unroll
    for (int off = 32; off; off >>= 1) m = fmaxf(m, __shfl_xor(m, off));

    float s = exp2f((v0.x - m) * LOG2E) + exp2f((v0.y - m) * LOG2E)
            + exp2f((v0.z - m) * LOG2E) + exp2f((v0.w - m) * LOG2E)
            + exp2f((v1.x - m) * LOG2E) + exp2f((v1.y - m) * LOG2E)
            + exp2f((v1.z - m) * LOG2E) + exp2f((v1.w - m) * LOG2E);
    #pragma unroll
    for (int off = 32; off; off >>= 1) s += __shfl_xor(s, off);

    if (lane < L / 4) {  // 50 lanes, 4 targets each
        const int4 tv = *(const int4*)(tgt + b * L + lane * 4);
        const float c0 = m * LOG2E + log2f(s);   // log2 p = x*LOG2E - c0
        float p0 = e[tv.x] * LOG2E - c0;
        float p1 = e[tv.y] * LOG2E - c0;
        float p2 = e[tv.z] * LOG2E - c0;
        float p3 = e[tv.w] * LOG2E - c0;
        uint2 w;
        w.x = (uint32_t)f2bf(p0) | ((uint32_t)f2bf(p1) << 16);
        w.y = (uint32_t)f2bf(p2) | ((uint32_t)f2bf(p3) << 16);
        *(uint2*)(emit + (size_t)row * L + lane * 4) = w;
    }
}

// Kernel B: exact log2-domain alignment DP. One wave per batch element.
// Lane holds l = 4*lane .. 4*lane+3 (lanes 0..49 active for L=200).
// A[l] = p2[t,l] + logaddexp2(A[l], A[l-1]); no rescaling needed.
__global__ __launch_bounds__(64, 1) void dp_kernel(
    const uint16_t* __restrict__ emit, float* __restrict__ partial)
{
    const int b    = blockIdx.x;
    const int lane = threadIdx.x;
    const int l0   = lane * 4;
    const bool act = (l0 < L);
    const uint16_t* rowp = emit + (size_t)b * T * L + l0;

    float A0 = NEG, A1 = NEG, A2 = NEG, A3 = NEG;
    bool first = true;   // inject log2 alpha[-1]=0 on the very first step

    uint2 bufA[CH], bufB[CH], bufC[CH], bufD[CH];

#define LOADC(BUF, CBASE) do {                                               \
    const uint16_t* _p = rowp + (size_t)(CBASE) * (CH * L);                  \
    _Pragma("unroll")                                                        \
    for (int _j = 0; _j < CH; ++_j)                                          \
        BUF[_j] = act ? *(const uint2*)(_p + _j * L) : make_uint2(0u, 0u);   \
} while (0)

#define PROC(BUF) do {                                                       \
    _Pragma("unroll")                                                        \
    for (int _j = 0; _j < CH; ++_j) {                                        \
        uint2 _v = BUF[_j];                                                  \
        float _p0 = __uint_as_float(_v.x << 16);                             \
        float _p1 = __uint_as_float(_v.x & 0xffff0000u);                     \
        float _p2 = __uint_as_float(_v.y << 16);                             \
        float _p3 = __uint_as_float(_v.y & 0xffff0000u);                     \
        float _up = __shfl_up(A3, 1);                                        \
        float _fix = (_j == 0 && first) ? 0.0f : NEG;                        \
        float _s0 = (lane == 0) ? _fix : _up;                                \
        float _n0 = _p0 + lae2(A0, _s0);                                     \
        float _n1 = _p1 + lae2(A1, A0);                                      \
        float _n2 = _p2 + lae2(A2, A1);                                      \
        float _n3 = _p3 + lae2(A3, A2);                                      \
        A0 = _n0; A1 = _n1; A2 = _n2; A3 = _n3;                              \
    }                                                                        \
    first = false;                                                           \
} while (0)

    LOADC(bufA, 0);
    LOADC(bufB, 1);
    for (int c = 0; c < NC; c += 4) {
        LOADC(bufC, c + 2);
        LOADC(bufD, c + 3);
        PROC(bufA);
        PROC(bufB);
        if (c + 4 < NC) { LOADC(bufA, c + 4); LOADC(bufB, c + 5); }
        PROC(bufC);
        PROC(bufD);
    }

#undef LOADC
#undef PROC

    // log2 alpha[T-1, L-1] lives in lane 49's A3 (l = 199); convert to ln
    if (lane == 49) {
        partial[b] = A3 * LN2;
    }
}

// Kernel C: loss = -mean_b log alpha_b
__global__ __launch_bounds__(64) void reduce_kernel(
    const float* __restrict__ partial, float* __restrict__ out)
{
    const int lane = threadIdx.x;
    float v = (lane < B) ? partial[lane] : 0.f;
    #pragma unroll
    for (int off = 32; off; off >>= 1) v += __shfl_xor(v, off);
    if (lane == 0) out[0] = -v * (1.0f / (float)B);
}

extern "C" void kernel_launch(void* const* d_in, const int* in_sizes, int n_in,
                              void* d_out, int out_size, void* d_ws, size_t ws_size,
                              hipStream_t stream) {
    const float* x   = (const float*)d_in[0];   // [B,T,C] fp32
    const int*   tgt = (const int*)d_in[1];     // [B,L] int32
    uint16_t* emit   = (uint16_t*)d_ws;         // [B,T,L] bf16 log2-probs (51.2 MB)
    float* partial   = (float*)((char*)d_ws + (size_t)B * T * L * sizeof(uint16_t));
    float* out       = (float*)d_out;

    emit_kernel<<<B * T / 4, 256, 0, stream>>>(x, tgt, emit);
    dp_kernel<<<B, 64, 0, stream>>>(emit, partial);
    reduce_kernel<<<1, 64, 0, stream>>>(partial, out);
}